// Round 12
// baseline (447.005 us; speedup 1.0000x reference)
//
#include <hip/hip_runtime.h>
#include <hip/hip_fp16.h>

// GAT layer: messages = X@Wm^T; e = lrelu(sf[src]+st[dst]); softmax over dst;
// merged = segsum(alpha * messages[src]); out = sig(c)*(X@Wr^T) + relu(merged).
//
// R9 post-mortem: fused f32-GEMM∥scatter = 145us; the f32 VALU GEMM (~100us,
// 33 TF effective) is the structural floor. R10-R12 (third submit; two broker
// timeouts): split-fp16 MFMA GEMM — x = xh+xl, W = wh+wl (fp16 hi/lo),
// X@W^T = xh@wh + xh@wl + xl@wh via 3x mfma_f32_16x16x32_f16 (f32 acc,
// residual ~2^-22 -> absmax unchanged). W pre-split + pre-swizzled into
// per-lane frag order (one dwordx4 per frag). A/B frag layout: row|col =
// lane&15, k = 8*(lane>>4)+elem. C/D: col = lane&15, row = (lane>>4)*4+reg
// (m89-verified). New LDS 17.5KB -> fused scatter keeps occupancy (R9 fix).

#define DD 128
#define NPB 32           // nodes per block in the GEMM kernel
#define LEAKY 0.01f
#define BSH 3            // log2(nodes per bucket)
#define BSZ 8            // nodes per bucket

typedef _Float16 f16x8 __attribute__((ext_vector_type(8)));
typedef float f32x4 __attribute__((ext_vector_type(4)));

// ---------- L0: detect ∥ eye ∥ zero(bcnt)  (fused, independent) ----------
__global__ void k_init(const int* __restrict__ e, const float* __restrict__ Wr,
                       int* __restrict__ flag, int* __restrict__ bcnt, int nb) {
  const int b = blockIdx.x;
  if (b == 0) {
    if (threadIdx.x == 0) {
      int all0 = 1;
      for (int i = 0; i < 64; ++i)
        if (e[2 * i + 1] != 0) { all0 = 0; break; }
      flag[0] = all0;  // 1 -> int64 layout
    }
  } else if (b == 1) {
    __shared__ int ok_s;
    if (threadIdx.x == 0) ok_s = 1;
    __syncthreads();
    int ok = 1;
    for (int i = threadIdx.x; i < DD * DD; i += 256) {
      float expect = ((i >> 7) == (i & (DD - 1))) ? 1.f : 0.f;
      if (Wr[i] != expect) ok = 0;
    }
    if (!ok) ok_s = 0;  // benign race: all writers write 0
    __syncthreads();
    if (threadIdx.x == 0) flag[1] = ok_s;
  } else {
    int i = (b - 2) * 256 + threadIdx.x;
    if (i < nb) bcnt[i] = 0;
  }
}

// ---------- L1: W hi/lo split + frag swizzle ∥ bucket-count ----------
// Swizzled table index i = ((ct*4 + c)*64 + lane)*8 + j  (ct=col-tile of 16,
// c=k-chunk of 32). Element = W[col][k], col = 16*ct + (lane&15),
// k = 32*c + 8*(lane>>4) + j. One dwordx4 per lane-frag in the GEMM.
__global__ void k_prep(const float* __restrict__ Wm, const float* __restrict__ Wr,
                       __half* __restrict__ Bmh, __half* __restrict__ Bml,
                       __half* __restrict__ Brh, __half* __restrict__ Brl,
                       const int* __restrict__ edges, int n_edges, int n_nodes,
                       const int* __restrict__ flag, int* __restrict__ bcnt) {
  const int b = blockIdx.x;
  if (b < 64) {
    int i = b * 256 + threadIdx.x;       // 0..16383
    int j = i & 7, l = (i >> 3) & 63, c = (i >> 9) & 3, ct = i >> 11;
    int k = 32 * c + 8 * (l >> 4) + j;
    int col = 16 * ct + (l & 15);
    float wm = Wm[col * DD + k];
    __half h = __float2half(wm);
    Bmh[i] = h;
    Bml[i] = __float2half(wm - __half2float(h));
    float wr = Wr[col * DD + k];
    __half h2 = __float2half(wr);
    Brh[i] = h2;
    Brl[i] = __float2half(wr - __half2float(h2));
  } else {
    int i = (b - 64) * 256 + threadIdx.x;
    if (i < n_edges) {
      int d = flag[0] ? ((const int2*)edges)[n_edges + i].x : edges[n_edges + i];
      if ((unsigned)d < (unsigned)n_nodes) atomicAdd(&bcnt[d >> BSH], 1);
    }
  }
}

// ---------- 3-level scan over nb buckets ----------
__global__ __launch_bounds__(256) void k_scan_a(const int* __restrict__ cnt, int n,
                                                int* __restrict__ outp,
                                                int* __restrict__ bsum) {
  __shared__ int lds[256];
  const int t = threadIdx.x;
  const int base = blockIdx.x * 1024 + t * 4;
  int v0 = 0, v1 = 0, v2 = 0, v3 = 0;
  if (base + 3 < n) {
    int4 q = *(const int4*)(cnt + base);
    v0 = q.x; v1 = q.y; v2 = q.z; v3 = q.w;
  } else {
    if (base + 0 < n) v0 = cnt[base + 0];
    if (base + 1 < n) v1 = cnt[base + 1];
    if (base + 2 < n) v2 = cnt[base + 2];
    if (base + 3 < n) v3 = cnt[base + 3];
  }
  const int tsum = v0 + v1 + v2 + v3;
  int val = tsum;
  lds[t] = val;
  __syncthreads();
  for (int off = 1; off < 256; off <<= 1) {
    int a = (t >= off) ? lds[t - off] : 0;
    __syncthreads();
    val += a;
    lds[t] = val;
    __syncthreads();
  }
  int o0 = val - tsum;
  int o1 = o0 + v0, o2 = o1 + v1, o3 = o2 + v2;
  if (base + 0 < n) outp[base + 0] = o0;
  if (base + 1 < n) outp[base + 1] = o1;
  if (base + 2 < n) outp[base + 2] = o2;
  if (base + 3 < n) outp[base + 3] = o3;
  if (t == 255) bsum[blockIdx.x] = val;
}

__global__ void k_scan_b(int* __restrict__ bsum, int nbk,
                         int* __restrict__ bstart, int nb) {
  __shared__ int lds[256];
  const int t = threadIdx.x;
  int v = (t < nbk) ? bsum[t] : 0;
  int val = v;
  lds[t] = val;
  __syncthreads();
  for (int off = 1; off < 256; off <<= 1) {
    int a = (t >= off) ? lds[t - off] : 0;
    __syncthreads();
    val += a;
    lds[t] = val;
    __syncthreads();
  }
  if (t < nbk) bsum[t] = val - v;
  if (t == nbk - 1) bstart[nb] = val;
}

__global__ void k_scan_c(int* __restrict__ bstart, int* __restrict__ bcursor,
                         const int* __restrict__ bsum, int nb) {
  const int off = bsum[blockIdx.x];
  const int base = blockIdx.x * 1024 + threadIdx.x * 4;
#pragma unroll
  for (int c = 0; c < 4; ++c) {
    int idx = base + c;
    if (idx < nb) {
      int r = bstart[idx] + off;
      bstart[idx] = r;
      bcursor[idx] = r;
    }
  }
}

// ---------- L5: split-fp16 MFMA msg GEMM ∥ bucket scatter ----------
__global__ __launch_bounds__(256) void k_mscat(
    const float* __restrict__ x, const __half* __restrict__ Bmh,
    const __half* __restrict__ Bml, const __half* __restrict__ Brh,
    const __half* __restrict__ Brl, const float* __restrict__ attn_w,
    const float* __restrict__ coef, const int* __restrict__ flag, int n_nodes,
    __half* __restrict__ mh, float* __restrict__ s_from,
    float* __restrict__ s_to, float* __restrict__ out, int msg_blocks,
    const int* __restrict__ edges, int n_edges, int* __restrict__ bcursor,
    int* __restrict__ packed) {
  __shared__ __half Ah[2 * 4 * 64 * 8];   // 8 KiB  (X hi, frag-swizzled)
  __shared__ __half Al[2 * 4 * 64 * 8];   // 8 KiB  (X lo)
  __shared__ float lds_aw[2 * DD];        // 1 KiB
  __shared__ float sc[2][NPB][2];         // 512 B  (score partials per col-half)
  const int t = threadIdx.x;

  if ((int)blockIdx.x >= msg_blocks) {
    // ---- scatter part (no LDS use; still thread-limited occupancy) ----
    int i = (blockIdx.x - msg_blocks) * 256 + t;
    if (i < n_edges) {
      int d, s;
      if (flag[0]) {
        d = ((const int2*)edges)[n_edges + i].x;
        s = ((const int2*)edges)[i].x;
      } else {
        d = edges[n_edges + i];
        s = edges[i];
      }
      if ((unsigned)d < (unsigned)n_nodes) {
        if ((unsigned)s >= (unsigned)n_nodes) s = 0;
        int pos = atomicAdd(&bcursor[d >> BSH], 1);
        packed[pos] = (s << BSH) | (d & (BSZ - 1));
      }
    }
    return;
  }

  // ---- MFMA GEMM part ----
  const int nb0 = blockIdx.x * NPB;
  const int nvalid = min(NPB, n_nodes - nb0);

  // stage X -> fp16 hi/lo, frag-swizzled. float4 f4: n=f4>>5, k0=4*(f4&31).
  const float4* xs = (const float4*)(x + (size_t)nb0 * DD);
#pragma unroll
  for (int i = 0; i < 4; ++i) {
    int f4 = t + i * 256;
    int n = f4 >> 5, q = f4 & 31;
    int c = q >> 3, hi = (q & 7) >> 1, j0 = (q & 1) * 4;
    int nt2 = n >> 4, row = n & 15;
    int l2 = row | (hi << 4);
    int h0 = ((nt2 * 4 + c) * 64 + l2) * 8 + j0;   // half-index, %4==0
    float4 v = (n < nvalid) ? xs[f4] : make_float4(0.f, 0.f, 0.f, 0.f);
    __half hx = __float2half(v.x), hy = __float2half(v.y),
           hz = __float2half(v.z), hw = __float2half(v.w);
    union { __half2 h2[2]; uint2 u; } ph, pl;
    ph.h2[0] = __halves2half2(hx, hy);
    ph.h2[1] = __halves2half2(hz, hw);
    pl.h2[0] = __halves2half2(__float2half(v.x - __half2float(hx)),
                              __float2half(v.y - __half2float(hy)));
    pl.h2[1] = __halves2half2(__float2half(v.z - __half2float(hz)),
                              __float2half(v.w - __half2float(hw)));
    ((uint2*)Ah)[h0 >> 2] = ph.u;
    ((uint2*)Al)[h0 >> 2] = pl.u;
  }
  lds_aw[t] = attn_w[t];
  __syncthreads();

  const int l = t & 63;
  const int wv = t >> 6;
  const int nt = wv & 1;    // node sub-tile (16 nodes)
  const int ch = wv >> 1;   // col half (64 cols)

  f32x4 acc[4] = {{0,0,0,0},{0,0,0,0},{0,0,0,0},{0,0,0,0}};
  {
    const f16x8* BH = (const f16x8*)Bmh;
    const f16x8* BL = (const f16x8*)Bml;
#pragma unroll
    for (int c = 0; c < 4; ++c) {
      f16x8 ah = *(const f16x8*)(Ah + ((nt * 4 + c) * 64 + l) * 8);
      f16x8 al = *(const f16x8*)(Al + ((nt * 4 + c) * 64 + l) * 8);
#pragma unroll
      for (int ci = 0; ci < 4; ++ci) {
        int ct = ch * 4 + ci;
        f16x8 bh = BH[(ct * 4 + c) * 64 + l];
        f16x8 bl = BL[(ct * 4 + c) * 64 + l];
        acc[ci] = __builtin_amdgcn_mfma_f32_16x16x32_f16(ah, bh, acc[ci], 0, 0, 0);
        acc[ci] = __builtin_amdgcn_mfma_f32_16x16x32_f16(ah, bl, acc[ci], 0, 0, 0);
        acc[ci] = __builtin_amdgcn_mfma_f32_16x16x32_f16(al, bh, acc[ci], 0, 0, 0);
      }
    }
  }

  // epilogue A: fp16 message store (C/D: col=l&15, row=(l>>4)*4+r)
#pragma unroll
  for (int ci = 0; ci < 4; ++ci) {
#pragma unroll
    for (int r = 0; r < 4; ++r) {
      int node = nb0 + 16 * nt + (l >> 4) * 4 + r;
      int col = 64 * ch + 16 * ci + (l & 15);
      if (node < n_nodes) mh[(size_t)node * DD + col] = __float2half(acc[ci][r]);
    }
  }
  // scores: per-node dot with attn_w halves; reduce over the 16-lane col group
#pragma unroll
  for (int r = 0; r < 4; ++r) {
    float pf = 0.f, pt = 0.f;
#pragma unroll
    for (int ci = 0; ci < 4; ++ci) {
      int col = 64 * ch + 16 * ci + (l & 15);
      float m = acc[ci][r];
      pf = fmaf(m, lds_aw[col], pf);
      pt = fmaf(m, lds_aw[DD + col], pt);
    }
#pragma unroll
    for (int msk = 1; msk < 16; msk <<= 1) {
      pf += __shfl_xor(pf, msk, 64);
      pt += __shfl_xor(pt, msk, 64);
    }
    if ((l & 15) == 0) {
      int li = 16 * nt + (l >> 4) * 4 + r;
      sc[ch][li][0] = pf;
      sc[ch][li][1] = pt;
    }
  }
  __syncthreads();
  if (t < NPB) {
    int node = nb0 + t;
    if (node < n_nodes) {
      s_from[node] = sc[0][t][0] + sc[1][t][0];
      s_to[node]   = sc[0][t][1] + sc[1][t][1];
    }
  }

  // phase B: passthrough
  const float sig = 1.f / (1.f + __expf(-coef[0]));
  if (flag[1]) {
    // W_res == I: out = sig * x, reconstructed hi+lo (err ~2^-21, negligible)
    float4* od = (float4*)(out + (size_t)nb0 * DD);
#pragma unroll
    for (int i = 0; i < 4; ++i) {
      int f4 = t + i * 256;
      int n = f4 >> 5, q = f4 & 31;
      if (n < nvalid) {
        int c = q >> 3, hi = (q & 7) >> 1, j0 = (q & 1) * 4;
        int nt2 = n >> 4, row = n & 15;
        int l2 = row | (hi << 4);
        int h0 = ((nt2 * 4 + c) * 64 + l2) * 8 + j0;
        union { __half2 h2[2]; uint2 u; } ph, pl;
        ph.u = ((const uint2*)Ah)[h0 >> 2];
        pl.u = ((const uint2*)Al)[h0 >> 2];
        float2 a0 = __half22float2(ph.h2[0]);
        float2 a1 = __half22float2(ph.h2[1]);
        float2 b0 = __half22float2(pl.h2[0]);
        float2 b1 = __half22float2(pl.h2[1]);
        float4 v;
        v.x = sig * (a0.x + b0.x);
        v.y = sig * (a0.y + b0.y);
        v.z = sig * (a1.x + b1.x);
        v.w = sig * (a1.y + b1.y);
        od[f4] = v;
      }
    }
  } else {
    // fallback: full split-MFMA GEMM vs W_res, f32 store
    f32x4 acr[4] = {{0,0,0,0},{0,0,0,0},{0,0,0,0},{0,0,0,0}};
    const f16x8* BH = (const f16x8*)Brh;
    const f16x8* BL = (const f16x8*)Brl;
#pragma unroll
    for (int c = 0; c < 4; ++c) {
      f16x8 ah = *(const f16x8*)(Ah + ((nt * 4 + c) * 64 + l) * 8);
      f16x8 al = *(const f16x8*)(Al + ((nt * 4 + c) * 64 + l) * 8);
#pragma unroll
      for (int ci = 0; ci < 4; ++ci) {
        int ct = ch * 4 + ci;
        f16x8 bh = BH[(ct * 4 + c) * 64 + l];
        f16x8 bl = BL[(ct * 4 + c) * 64 + l];
        acr[ci] = __builtin_amdgcn_mfma_f32_16x16x32_f16(ah, bh, acr[ci], 0, 0, 0);
        acr[ci] = __builtin_amdgcn_mfma_f32_16x16x32_f16(ah, bl, acr[ci], 0, 0, 0);
        acr[ci] = __builtin_amdgcn_mfma_f32_16x16x32_f16(al, bh, acr[ci], 0, 0, 0);
      }
    }
#pragma unroll
    for (int ci = 0; ci < 4; ++ci) {
#pragma unroll
      for (int r = 0; r < 4; ++r) {
        int node = nb0 + 16 * nt + (l >> 4) * 4 + r;
        int col = 64 * ch + 16 * ci + (l & 15);
        if (node < n_nodes) out[(size_t)node * DD + col] = sig * acr[ci][r];
      }
    }
  }
}

// ---------- within-bucket counting sort -> node-sorted CSR ----------
__global__ __launch_bounds__(256) void k_bsort(
    const int* __restrict__ bstart, const int* __restrict__ packed,
    int nb, int n_nodes, int n_edges_total,
    int* __restrict__ srcs, int* __restrict__ row_start) {
  const int lane = threadIdx.x & 63;
  const int b = blockIdx.x * 4 + (threadIdx.x >> 6);
  if (b >= nb) return;
  const int start = bstart[b], end = bstart[b + 1];
  const int nbase = b << BSH;
  if (b == 0 && lane == 0) row_start[n_nodes] = n_edges_total;

  int c0 = 0, c1 = 0, c2 = 0, c3 = 0, c4 = 0, c5 = 0, c6 = 0, c7 = 0;
  for (int cb = start; cb < end; cb += 64) {
    const bool act = (cb + lane) < end;
    const int u = act ? packed[cb + lane] : 0;
    const int dl = u & (BSZ - 1);
    const unsigned long long b0 = __ballot(act && (dl & 1));
    const unsigned long long b1 = __ballot(act && (dl & 2));
    const unsigned long long b2 = __ballot(act && (dl & 4));
    const unsigned long long ba = __ballot(act);
    c0 += __popcll(~b0 & ~b1 & ~b2 & ba);
    c1 += __popcll( b0 & ~b1 & ~b2 & ba);
    c2 += __popcll(~b0 &  b1 & ~b2 & ba);
    c3 += __popcll( b0 &  b1 & ~b2 & ba);
    c4 += __popcll(~b0 & ~b1 &  b2 & ba);
    c5 += __popcll( b0 & ~b1 &  b2 & ba);
    c6 += __popcll(~b0 &  b1 &  b2 & ba);
    c7 += __popcll( b0 &  b1 &  b2 & ba);
  }
  const int o0 = 0, o1 = o0 + c0, o2 = o1 + c1, o3 = o2 + c2, o4 = o3 + c3,
            o5 = o4 + c4, o6 = o5 + c5, o7 = o6 + c6;
  if (lane == 0) {
    if (nbase + 0 < n_nodes) row_start[nbase + 0] = start + o0;
    if (nbase + 1 < n_nodes) row_start[nbase + 1] = start + o1;
    if (nbase + 2 < n_nodes) row_start[nbase + 2] = start + o2;
    if (nbase + 3 < n_nodes) row_start[nbase + 3] = start + o3;
    if (nbase + 4 < n_nodes) row_start[nbase + 4] = start + o4;
    if (nbase + 5 < n_nodes) row_start[nbase + 5] = start + o5;
    if (nbase + 6 < n_nodes) row_start[nbase + 6] = start + o6;
    if (nbase + 7 < n_nodes) row_start[nbase + 7] = start + o7;
  }
  int r0 = o0, r1 = o1, r2 = o2, r3 = o3, r4 = o4, r5 = o5, r6 = o6, r7 = o7;
  for (int cb = start; cb < end; cb += 64) {
    const bool act = (cb + lane) < end;
    const int u = act ? packed[cb + lane] : 0;
    const int dl = u & (BSZ - 1);
    const unsigned long long b0 = __ballot(act && (dl & 1));
    const unsigned long long b1 = __ballot(act && (dl & 2));
    const unsigned long long b2 = __ballot(act && (dl & 4));
    const unsigned long long ba = __ballot(act);
    const unsigned long long m0 = (dl & 1) ? b0 : ~b0;
    const unsigned long long m1 = (dl & 2) ? b1 : ~b1;
    const unsigned long long m2 = (dl & 4) ? b2 : ~b2;
    const unsigned long long mymask = m0 & m1 & m2 & ba;
    const int rank = __popcll(mymask & ((1ull << lane) - 1ull));
    int basep = r0;
    basep = (dl == 1) ? r1 : basep;
    basep = (dl == 2) ? r2 : basep;
    basep = (dl == 3) ? r3 : basep;
    basep = (dl == 4) ? r4 : basep;
    basep = (dl == 5) ? r5 : basep;
    basep = (dl == 6) ? r6 : basep;
    basep = (dl == 7) ? r7 : basep;
    if (act) srcs[start + basep + rank] = u >> BSH;
    r0 += __popcll(~b0 & ~b1 & ~b2 & ba);
    r1 += __popcll( b0 & ~b1 & ~b2 & ba);
    r2 += __popcll(~b0 &  b1 & ~b2 & ba);
    r3 += __popcll( b0 &  b1 & ~b2 & ba);
    r4 += __popcll(~b0 & ~b1 &  b2 & ba);
    r5 += __popcll( b0 & ~b1 &  b2 & ba);
    r6 += __popcll(~b0 &  b1 &  b2 & ba);
    r7 += __popcll( b0 &  b1 &  b2 & ba);
  }
}

// ---------- aggregation: one wave per node, branch-free, fp16 gather ----------
__global__ __launch_bounds__(256) void k_nagg(
    const int* __restrict__ row_start, const int* __restrict__ srcs,
    const float* __restrict__ s_from, const float* __restrict__ s_to,
    const __half* __restrict__ mh, int n_nodes, float* __restrict__ out) {
  const int lane = threadIdx.x & 63;
  const int v = blockIdx.x * 4 + (threadIdx.x >> 6);
  if (v >= n_nodes) return;
  const int start = row_start[v];
  const int end = row_start[v + 1];
  if (start >= end) return;  // degree 0: d_out row already = passthrough
  const float st = s_to[v];

  float wsum = 0.f;
  float ax = 0.f, ay = 0.f;  // lane owns columns 2*lane, 2*lane+1
  for (int cbase = start; cbase < end; cbase += 64) {
    const int cnt = min(64, end - cbase);
    int s = 0;
    float w = 0.f;
    if (lane < cnt) {
      s = srcs[cbase + lane];
      float xx = s_from[s] + st;
      xx = (xx >= 0.f) ? xx : LEAKY * xx;
      w = __expf(xx);  // no max-sub: softmax shift-invariant, e is O(1)
    }
    wsum += w;
#pragma unroll 8
    for (int i = 0; i < cnt; ++i) {   // branch-free body -> loads pipeline
      int si = __shfl(s, i, 64);
      float wi = __shfl(w, i, 64);
      const float2 mf =
          __half22float2(((const __half2*)(mh + (size_t)si * DD))[lane]);
      ax = fmaf(wi, mf.x, ax);
      ay = fmaf(wi, mf.y, ay);
    }
  }
#pragma unroll
  for (int m = 32; m; m >>= 1) wsum += __shfl_xor(wsum, m, 64);
  const float inv = 1.f / wsum;
  ax *= inv; ay *= inv;
  ax = (ax > 0.f) ? ax : 0.f;  // relu(merged)
  ay = (ay > 0.f) ? ay : 0.f;
  float2* orow = (float2*)(out + (size_t)v * DD);
  float2 po = orow[lane];      // passthrough written by msg phase
  orow[lane] = make_float2(po.x + ax, po.y + ay);
}

// ---------- host ----------
extern "C" void kernel_launch(void* const* d_in, const int* in_sizes, int n_in,
                              void* d_out, int out_size, void* d_ws, size_t ws_size,
                              hipStream_t stream) {
  const float* x = (const float*)d_in[0];
  const int* edges = (const int*)d_in[1];
  const float* Wm = (const float*)d_in[2];
  const float* aw = (const float*)d_in[3];
  const float* Wr = (const float*)d_in[4];
  const float* coef = (const float*)d_in[5];
  float* out = (float*)d_out;

  const int N = in_sizes[0] / DD;  // 100000
  const int E = in_sizes[1] / 2;   // 1600000
  const int nb = (N + BSZ - 1) / BSZ;  // 12500 buckets

  // Workspace budget check: never scribble past d_ws.
  const size_t need = ((size_t)N * DD * 2 + 256)       // mh (fp16 messages)
                    + 2 * ((size_t)N * 4 + 256)        // s_from, s_to
                    + 4 * ((size_t)DD * DD * 2 + 256)  // Bmh, Bml, Brh, Brl
                    + 3 * ((size_t)(nb + 1) * 4 + 512) // bcnt, bstart, bcursor
                    + ((size_t)(N + 1) * 4 + 256)      // row_start
                    + 2048                              // flags + bsum
                    + 2 * ((size_t)E * 4 + 256);        // packed, srcs
  if (ws_size < need) return;  // refuse to run rather than corrupt memory

  char* w = (char*)d_ws;
  auto alloc = [&](size_t bytes) {
    char* p = w;
    w += (bytes + 255) & ~(size_t)255;
    return p;
  };
  __half* mh     = (__half*)alloc((size_t)N * DD * 2);
  float* s_from  = (float*)alloc((size_t)N * 4);
  float* s_to    = (float*)alloc((size_t)N * 4);
  __half* Bmh    = (__half*)alloc((size_t)DD * DD * 2);
  __half* Bml    = (__half*)alloc((size_t)DD * DD * 2);
  __half* Brh    = (__half*)alloc((size_t)DD * DD * 2);
  __half* Brl    = (__half*)alloc((size_t)DD * DD * 2);
  int*   bcnt    = (int*)alloc((size_t)nb * 4);
  int*   bstart  = (int*)alloc((size_t)(nb + 1) * 4);
  int*   bcursor = (int*)alloc((size_t)nb * 4);
  int*   row_start = (int*)alloc((size_t)(N + 1) * 4);
  int*   flag    = (int*)alloc(256);   // flag[0]=int64 layout, flag[1]=Wr==I
  int*   bsum    = (int*)alloc(256 * 4);
  int*   packed  = (int*)alloc((size_t)E * 4);
  int*   srcs    = (int*)alloc((size_t)E * 4);

  const int MB = (N + NPB - 1) / NPB;      // 3125 msg blocks
  const int EB = (E + 255) / 256;          // 6250 edge blocks
  const int ZB = (nb + 255) / 256;         // zero blocks
  const int SB = (nb + 1023) / 1024;       // 13 scan blocks

  k_init<<<2 + ZB, 256, 0, stream>>>(edges, Wr, flag, bcnt, nb);
  k_prep<<<64 + EB, 256, 0, stream>>>(Wm, Wr, Bmh, Bml, Brh, Brl,
                                      edges, E, N, flag, bcnt);
  k_scan_a<<<SB, 256, 0, stream>>>(bcnt, nb, bstart, bsum);
  k_scan_b<<<1, 256, 0, stream>>>(bsum, SB, bstart, nb);
  k_scan_c<<<SB, 256, 0, stream>>>(bstart, bcursor, bsum, nb);
  k_mscat<<<MB + EB, 256, 0, stream>>>(x, Bmh, Bml, Brh, Brl, aw, coef, flag, N,
                                       mh, s_from, s_to, out, MB,
                                       edges, E, bcursor, packed);
  k_bsort<<<(nb + 3) / 4, 256, 0, stream>>>(bstart, packed, nb, N, E,
                                            srcs, row_start);
  k_nagg<<<(N + 3) / 4, 256, 0, stream>>>(row_start, srcs, s_from, s_to,
                                          mh, N, out);
}